// Round 1
// baseline (1848.134 us; speedup 1.0000x reference)
//
#include <hip/hip_runtime.h>
#include <cstdint>
#include <cstddef>

// ---------------- constants ----------------
constexpr int L   = 2048;   // sequence length
constexpr int DM  = 1024;   // model dim
constexpr int NH  = 16;     // heads
constexpr int DK  = 64;     // head dim
constexpr int SSTRIDE = 2052; // padded LDS score-row stride (floats): 2052%32=4 -> 2-way (free) bank conflicts

typedef unsigned short u16;
typedef u16   u16x8  __attribute__((ext_vector_type(8)));
typedef __bf16 bf16x8 __attribute__((ext_vector_type(8)));
typedef float f32x4  __attribute__((ext_vector_type(4)));

static __device__ __forceinline__ bf16x8 as_bf(u16x8 u){
  union { u16x8 a; bf16x8 b; } x; x.a = u; return x.b;
}
// f32 -> bf16 with round-to-nearest-even
static __device__ __forceinline__ u16 f2b(float f){
  union { float f; unsigned u; } x; x.f = f;
  unsigned r = x.u + 0x7FFFu + ((x.u >> 16) & 1u);
  return (u16)(r >> 16);
}
#define MFMA16(a,b,c) __builtin_amdgcn_mfma_f32_16x16x32_bf16(as_bf(a), as_bf(b), (c), 0, 0, 0)

// ---------------- f32 -> bf16 elementwise convert (4 elems/thread) ----------------
__global__ __launch_bounds__(256) void cvt_kernel(const float* __restrict__ x, u16* __restrict__ y){
  int i = (blockIdx.x * 256 + threadIdx.x) * 4;
  float4 v = *(const float4*)(x + i);
  union { u16 s[4]; uint2 u; } o;
  o.s[0] = f2b(v.x); o.s[1] = f2b(v.y); o.s[2] = f2b(v.z); o.s[3] = f2b(v.w);
  *(uint2*)(y + i) = o.u;
}

// ---------------- transpose + convert: W (k,n) f32 -> WT (n,k) bf16 ----------------
__global__ __launch_bounds__(256) void tcvt_kernel(const float* __restrict__ Wm, u16* __restrict__ WT){
  __shared__ float tile[32][33];
  int bx = blockIdx.x * 32;          // n
  int by = blockIdx.y * 32;          // k
  int tx = threadIdx.x & 31;
  int ty = threadIdx.x >> 5;         // 0..7
  #pragma unroll
  for (int j = 0; j < 32; j += 8)
    tile[ty + j][tx] = Wm[(size_t)(by + ty + j) * DM + bx + tx];
  __syncthreads();
  #pragma unroll
  for (int j = 0; j < 32; j += 8)
    WT[(size_t)(bx + ty + j) * DM + by + tx] = f2b(tile[tx][ty + j]);
}

// ---------------- gates = sigmoid(q @ Wg + bg), one wave per row ----------------
__global__ __launch_bounds__(256) void gate_kernel(const float* __restrict__ q,
                                                   const float* __restrict__ Wg,
                                                   const float* __restrict__ bg,
                                                   float* __restrict__ gates){
  int row  = blockIdx.x * 4 + (threadIdx.x >> 6);
  int lane = threadIdx.x & 63;
  float s = 0.f;
  #pragma unroll
  for (int j = 0; j < 16; j++) s += q[(size_t)row * DM + j * 64 + lane] * Wg[j * 64 + lane];
  #pragma unroll
  for (int off = 32; off > 0; off >>= 1) s += __shfl_down(s, off);
  if (lane == 0) gates[row] = 1.f / (1.f + __expf(-(s + bg[0])));
}

// ---------------- GEMM: C(M=2048 x N=1024) = A(2048x1024) @ W(1024x1024) + bias ----------------
// A bf16: AMODE 0 = plain row-major (m,k); AMODE 1 = head-chunked (k/64, m, k%64)
// WT bf16 in (n,k) layout.
// SMODE 0 = bf16 out in (n/64, m, n%64) head layout; SMODE 1 = bf16 out in (n/64, n%64, m) (V^T);
// SMODE 2 = f32 row-major (m,n).
template<int AMODE, int SMODE>
__global__ __launch_bounds__(256) void gemm_kernel(const u16* __restrict__ A,
                                                   const u16* __restrict__ WT,
                                                   const float* __restrict__ bias,
                                                   void* __restrict__ Cout){
  __shared__ u16 As[64][72];   // (m,k) k-contig, +8 pad -> 2-way conflicts only
  __shared__ u16 Bs[64][72];   // (n,k) k-contig
  int m0 = blockIdx.y * 64, n0 = blockIdx.x * 64;
  int tid = threadIdx.x;
  int w = tid >> 6, lane = tid & 63, lr = lane & 15, quad = lane >> 4;
  int lrow = tid >> 2;           // 0..63
  int lk   = (tid & 3) * 16;     // 0,16,32,48

  f32x4 acc[4];
  #pragma unroll
  for (int t = 0; t < 4; t++) acc[t] = (f32x4){0.f,0.f,0.f,0.f};

  for (int kt = 0; kt < 16; ++kt){
    int k0 = kt * 64;
    const u16* ap;
    if (AMODE == 0) ap = A + (size_t)(m0 + lrow) * DM + k0 + lk;
    else            ap = A + (size_t)(k0 >> 6) * (L * DK) + (size_t)(m0 + lrow) * DK + lk;
    u16x8 a0 = *(const u16x8*)ap;
    u16x8 a1 = *(const u16x8*)(ap + 8);
    const u16* bp = WT + (size_t)(n0 + lrow) * DM + k0 + lk;
    u16x8 b0 = *(const u16x8*)bp;
    u16x8 b1 = *(const u16x8*)(bp + 8);
    *(u16x8*)&As[lrow][lk]     = a0;
    *(u16x8*)&As[lrow][lk + 8] = a1;
    *(u16x8*)&Bs[lrow][lk]     = b0;
    *(u16x8*)&Bs[lrow][lk + 8] = b1;
    __syncthreads();
    #pragma unroll
    for (int s = 0; s < 2; ++s){
      u16x8 af = *(u16x8*)&As[w * 16 + lr][s * 32 + quad * 8];
      #pragma unroll
      for (int t = 0; t < 4; ++t){
        u16x8 bf = *(u16x8*)&Bs[t * 16 + lr][s * 32 + quad * 8];
        acc[t] = MFMA16(af, bf, acc[t]);
      }
    }
    __syncthreads();
  }

  #pragma unroll
  for (int t = 0; t < 4; ++t){
    int n = n0 + t * 16 + lr;
    float bv = bias[n];
    #pragma unroll
    for (int i = 0; i < 4; ++i){
      int m = m0 + w * 16 + quad * 4 + i;
      float val = acc[t][i] + bv;
      if (SMODE == 0)      ((u16*)Cout)[(size_t)(n >> 6) * (L * DK) + (size_t)m * DK + (n & 63)] = f2b(val);
      else if (SMODE == 1) ((u16*)Cout)[(size_t)(n >> 6) * (L * DK) + (size_t)(n & 63) * L + m]  = f2b(val);
      else                 ((float*)Cout)[(size_t)m * DM + n] = val;
    }
  }
}

// ---------------- attention hop ----------------
// one block = (head h, 16-query tile m0). 256 threads = 4 waves.
// LDS: S[16][SSTRIDE] f32 (scores -> exp values).  131,328 B dynamic.
__global__ __launch_bounds__(256) void attn_kernel(const u16* __restrict__ curA,  // (16,2048,64) bf16
                                                   const u16* __restrict__ Kh,    // (16,2048,64) bf16
                                                   const u16* __restrict__ Vt,    // (16,64,2048) bf16
                                                   const float* __restrict__ gates, // (2048)
                                                   float* __restrict__ wout,      // this hop's (16,2048,2048) f32
                                                   u16* __restrict__ ctxb){       // (16,2048,64) bf16
  extern __shared__ float S[];
  __shared__ float red[16][17];
  __shared__ float rowm[16];
  __shared__ float rowf[16];   // gate/sum per row

  int h  = blockIdx.y;
  int m0 = blockIdx.x * 16;
  int tid = threadIdx.x;
  int w = tid >> 6, lane = tid & 63, lr = lane & 15, quad = lane >> 4;

  // A-fragments for this 16-query tile (dk=64 -> 2 k-steps), reused for all keys
  const u16* curp = curA + (size_t)h * L * DK + (size_t)(m0 + lr) * DK + quad * 8;
  u16x8 a0 = *(const u16x8*)curp;
  u16x8 a1 = *(const u16x8*)(curp + 32);

  // Phase 1: scores S(16 x 2048); wave w owns keys [w*512, w*512+512)
  const u16* kb = Kh + (size_t)h * L * DK;
  for (int nt = 0; nt < 32; ++nt){
    int key0 = w * 512 + nt * 16;
    const u16* kp = kb + (size_t)(key0 + lr) * DK + quad * 8;
    u16x8 b0 = *(const u16x8*)kp;
    u16x8 b1 = *(const u16x8*)(kp + 32);
    f32x4 acc = (f32x4){0.f,0.f,0.f,0.f};
    acc = MFMA16(a0, b0, acc);
    acc = MFMA16(a1, b1, acc);
    #pragma unroll
    for (int i = 0; i < 4; ++i)
      S[(quad * 4 + i) * SSTRIDE + key0 + lr] = acc[i] * 0.125f;  // *1/sqrt(dk)
  }
  __syncthreads();

  // Phase 2: row max, then exp in place + row sum. 16 threads per row.
  int r2 = tid >> 4, c2 = tid & 15;
  float* Srow = S + r2 * SSTRIDE + c2 * 128;
  float mx = -1e30f;
  for (int j = 0; j < 128; ++j) mx = fmaxf(mx, Srow[j]);
  red[r2][c2] = mx;
  __syncthreads();
  if (tid < 16){
    float m = red[tid][0];
    for (int j = 1; j < 16; ++j) m = fmaxf(m, red[tid][j]);
    rowm[tid] = m;
  }
  __syncthreads();
  float mrow = rowm[r2];
  float sm = 0.f;
  for (int j = 0; j < 128; ++j){
    float e = __expf(Srow[j] - mrow);
    Srow[j] = e;               // same-thread RMW: safe
    sm += e;
  }
  red[r2][c2] = sm;
  __syncthreads();
  if (tid < 16){
    float s = 0.f;
    for (int j = 0; j < 16; ++j) s += red[tid][j];
    rowf[tid] = gates[m0 + tid] / s;   // gate/sum
  }
  __syncthreads();

  // Phase 3: write gated weights (f32, coalesced float4)
  for (int r = 0; r < 16; ++r){
    float f = rowf[r];
    const float4* Sr = (const float4*)(S + r * SSTRIDE);
    float4* gp = (float4*)(wout + (size_t)h * L * L + (size_t)(m0 + r) * L);
    #pragma unroll
    for (int j = 0; j < 2; ++j){
      int idx = tid + 256 * j;     // 512 float4 per row
      float4 v = Sr[idx];
      float4 o; o.x = v.x * f; o.y = v.y * f; o.z = v.z * f; o.w = v.w * f;
      gp[idx] = o;
    }
  }

  // Phase 4: ctx(16 x 64) = W(16x2048) @ V(2048x64); wave w owns d-chunk w*16.
  // A-fragments converted f32->bf16 from LDS on the fly; gate/sum folded into epilogue scale.
  f32x4 acc = (f32x4){0.f,0.f,0.f,0.f};
  const u16* vb = Vt + (size_t)h * DK * L + (size_t)(w * 16 + lr) * L;
  const float* Sa = S + lr * SSTRIDE;
  for (int ks = 0; ks < 64; ++ks){
    int k0 = ks * 32 + quad * 8;
    float4 x0 = *(const float4*)(Sa + k0);
    float4 x1 = *(const float4*)(Sa + k0 + 4);
    union { u16 s[8]; u16x8 v; } af;
    af.s[0] = f2b(x0.x); af.s[1] = f2b(x0.y); af.s[2] = f2b(x0.z); af.s[3] = f2b(x0.w);
    af.s[4] = f2b(x1.x); af.s[5] = f2b(x1.y); af.s[6] = f2b(x1.z); af.s[7] = f2b(x1.w);
    u16x8 bf = *(const u16x8*)(vb + k0);
    acc = MFMA16(af.v, bf, acc);
  }
  u16* cp = ctxb + (size_t)h * L * DK;
  #pragma unroll
  for (int i = 0; i < 4; ++i){
    int row = quad * 4 + i;
    cp[(size_t)(m0 + row) * DK + w * 16 + lr] = f2b(acc[i] * rowf[row]);
  }
}

// ---------------- launch ----------------
extern "C" void kernel_launch(void* const* d_in, const int* in_sizes, int n_in,
                              void* d_out, int out_size, void* d_ws, size_t ws_size,
                              hipStream_t stream){
  const float* q  = (const float*)d_in[0];
  const float* k  = (const float*)d_in[1];
  const float* v  = (const float*)d_in[2];
  const float* Wq = (const float*)d_in[3];
  const float* bq = (const float*)d_in[4];
  const float* Wk = (const float*)d_in[5];
  const float* bk = (const float*)d_in[6];
  const float* Wv = (const float*)d_in[7];
  const float* bv = (const float*)d_in[8];
  const float* Wo = (const float*)d_in[9];
  const float* bo = (const float*)d_in[10];
  const float* Wg = (const float*)d_in[11];
  const float* bg = (const float*)d_in[12];
  const float* Wp = (const float*)d_in[13];
  const float* bp = (const float*)d_in[14];
  // hop_count fixed at 3 by setup (out_size implies it)

  const size_t MB = 1024 * 1024;
  char* ws = (char*)d_ws;
  u16* qb   = (u16*)(ws + 0 * MB);
  u16* kbuf = (u16*)(ws + 4 * MB);
  u16* vbuf = (u16*)(ws + 8 * MB);
  u16* WqT  = (u16*)(ws + 12 * MB);
  u16* WkT  = (u16*)(ws + 14 * MB);
  u16* WvT  = (u16*)(ws + 16 * MB);
  u16* WpT  = (u16*)(ws + 18 * MB);
  u16* WoT  = (u16*)(ws + 20 * MB);
  u16* Qh   = (u16*)(ws + 22 * MB);
  u16* Kh   = (u16*)(ws + 26 * MB);
  u16* Vt   = (u16*)(ws + 30 * MB);
  u16* curb = (u16*)(ws + 34 * MB);
  u16* ctxb = (u16*)(ws + 38 * MB);
  float* gates = (float*)(ws + 42 * MB);

  float* outp  = (float*)d_out;
  float* wbase = outp + (size_t)L * DM;             // weights after `out`
  const size_t HOPW = (size_t)NH * L * L;           // per-hop weight count

  // bf16 conversions
  cvt_kernel<<<2048, 256, 0, stream>>>(q, qb);
  cvt_kernel<<<2048, 256, 0, stream>>>(k, kbuf);
  cvt_kernel<<<2048, 256, 0, stream>>>(v, vbuf);
  dim3 tg(32, 32);
  tcvt_kernel<<<tg, 256, 0, stream>>>(Wq, WqT);
  tcvt_kernel<<<tg, 256, 0, stream>>>(Wk, WkT);
  tcvt_kernel<<<tg, 256, 0, stream>>>(Wv, WvT);
  tcvt_kernel<<<tg, 256, 0, stream>>>(Wp, WpT);
  tcvt_kernel<<<tg, 256, 0, stream>>>(Wo, WoT);

  gate_kernel<<<512, 256, 0, stream>>>(q, Wg, bg, gates);

  dim3 gg(16, 32);  // (n tiles, m tiles), 64x64
  gemm_kernel<0, 0><<<gg, 256, 0, stream>>>(qb,   WqT, bq, Qh);
  gemm_kernel<0, 0><<<gg, 256, 0, stream>>>(kbuf, WkT, bk, Kh);
  gemm_kernel<0, 1><<<gg, 256, 0, stream>>>(vbuf, WvT, bv, Vt);

  dim3 ag(L / 16, NH);                 // (128 query tiles, 16 heads)
  size_t slds = (size_t)16 * SSTRIDE * 4;   // 131,328 B

  attn_kernel<<<ag, 256, slds, stream>>>(Qh, Kh, Vt, gates, wbase + 0 * HOPW, ctxb);
  gemm_kernel<1, 0><<<gg, 256, 0, stream>>>(ctxb, WpT, bp, curb);
  attn_kernel<<<ag, 256, slds, stream>>>(curb, Kh, Vt, gates, wbase + 1 * HOPW, ctxb);
  gemm_kernel<1, 0><<<gg, 256, 0, stream>>>(ctxb, WpT, bp, curb);
  attn_kernel<<<ag, 256, slds, stream>>>(curb, Kh, Vt, gates, wbase + 2 * HOPW, ctxb);
  gemm_kernel<1, 2><<<gg, 256, 0, stream>>>(ctxb, WoT, bo, (void*)outp);
}